// Round 7
// baseline (52.424 us; speedup 1.0000x reference)
//
#include <hip/hip_runtime.h>

#define NPART 62
#define M     256
#define DD    256
#define NPOS  8
#define NNEG  248
#define MARG  0.2f
#define REC   512

// ---- ws layout (float units): recs + per-part sums only ----
#define R0      0
#define P0      (496 * REC)
#define WS_NEED ((size_t)(P0 + NPART) * 4)

#define OFF_HARD 15376
#define OFF_MD   15438
#define OFF_FN   15439

typedef _Float16 f16x8 __attribute__((ext_vector_type(8)));
typedef float    f32x4 __attribute__((ext_vector_type(4)));

__device__ __forceinline__ void cvt_split(float4 a, float4 b, f16x8& hi, f16x8& lo)
{
    float x[8] = {a.x, a.y, a.z, a.w, b.x, b.y, b.z, b.w};
#pragma unroll
    for (int j = 0; j < 8; ++j) {
        _Float16 h = (_Float16)x[j];
        hi[j] = h;
        lo[j] = (_Float16)(x[j] - (float)h);
    }
}

// ======================= fused convert + MFMA dist + mining =======================
#define PITCH 258
__global__ __launch_bounds__(512) void k_all(const float* __restrict__ F,
                                             const int* __restrict__ label,
                                             float* __restrict__ recs)
{
    __shared__ __align__(16) float region[32 * PITCH];   // dist tile, 33,024 B
    __shared__ float x2s[M];
    __shared__ float fullS[8][NNEG];
    __shared__ float fullC[8][NNEG];
    __shared__ float posbuf[8][NPOS];
    __shared__ float wred[16];

    const int bxr = blockIdx.x;                       // 496 = 8 XCD * 62
    const int swz = (bxr & 7) * 62 + (bxr >> 3);      // bijective; part's 8 tiles same-XCD
    const int p   = swz >> 3;
    const int ib  = (swz & 7) * 32;                   // anchor base
    const int t   = threadIdx.x;
    const int lane = t & 63;
    const int w    = t >> 6;                          // wave 0..7

    const float* Fp = F + (size_t)p * (M * DD);
    const int rfrag  = lane & 15;                     // row within 16-tile
    const int k0base = (lane >> 4) * 8;               // k-octet offset within 32-slab
    const int arow0  = ib + rfrag;                    // A rt=0 row (rt=1: +16)
    const int brow0  = w * 32 + rfrag;                // B c=0 row (c=1: +16)

    float x2a[2] = {0.f, 0.f};

    f32x4 acc[2][2];
#pragma unroll
    for (int rt = 0; rt < 2; ++rt)
#pragma unroll
        for (int c = 0; c < 2; ++c) acc[rt][c] = (f32x4){0.f, 0.f, 0.f, 0.f};

    // load fp32 slice for slab s, convert to f16 hi/lo fragments, fold x2 (B side)
    auto LOADCVT = [&](int s, f16x8 (&A)[2][2], f16x8 (&B)[2][2]) {
        const float* SB = Fp + s * 32 + k0base;
#pragma unroll
        for (int rt = 0; rt < 2; ++rt) {
            const float4* q = (const float4*)(SB + (arow0 + rt * 16) * 256);
            cvt_split(q[0], q[1], A[rt][0], A[rt][1]);
        }
#pragma unroll
        for (int c = 0; c < 2; ++c) {
            const float4* q = (const float4*)(SB + (brow0 + c * 16) * 256);
            float4 v0 = q[0], v1 = q[1];
            x2a[c] += v0.x * v0.x + v0.y * v0.y + v0.z * v0.z + v0.w * v0.w +
                      v1.x * v1.x + v1.y * v1.y + v1.z * v1.z + v1.w * v1.w;
            cvt_split(v0, v1, B[c][0], B[c][1]);
        }
    };

    // ---- barrier-free K-loop, s+1 prefetched+converted under s's MFMAs ----
    f16x8 cA[2][2], cB[2][2], nA[2][2], nB[2][2];
    LOADCVT(0, cA, cB);
#pragma unroll
    for (int s = 0; s < 8; ++s) {
        if (s < 7) LOADCVT(s + 1, nA, nB);
#pragma unroll
        for (int rt = 0; rt < 2; ++rt)
#pragma unroll
            for (int c = 0; c < 2; ++c) {
                acc[rt][c] = __builtin_amdgcn_mfma_f32_16x16x32_f16(cA[rt][0], cB[c][0], acc[rt][c], 0, 0, 0);
                acc[rt][c] = __builtin_amdgcn_mfma_f32_16x16x32_f16(cA[rt][0], cB[c][1], acc[rt][c], 0, 0, 0);
                acc[rt][c] = __builtin_amdgcn_mfma_f32_16x16x32_f16(cA[rt][1], cB[c][0], acc[rt][c], 0, 0, 0);
            }
        if (s < 7) {
#pragma unroll
            for (int rt = 0; rt < 2; ++rt)
#pragma unroll
                for (int h = 0; h < 2; ++h) { cA[rt][h] = nA[rt][h]; }
#pragma unroll
            for (int c = 0; c < 2; ++c)
#pragma unroll
                for (int h = 0; h < 2; ++h) { cB[c][h] = nB[c][h]; }
        }
    }

    // ---- x2: reduce across the 4 k-octet groups, publish to LDS ----
#pragma unroll
    for (int c = 0; c < 2; ++c) {
        x2a[c] += __shfl_xor(x2a[c], 16);
        x2a[c] += __shfl_xor(x2a[c], 32);
    }
    if (lane < 16) {
        x2s[w * 32 + rfrag]      = x2a[0];
        x2s[w * 32 + 16 + rfrag] = x2a[1];
    }
    __syncthreads();

    // ---- epilogue: dist -> LDS (C/D layout: col=lane&15, row=(lane>>4)*4+r) ----
    const int cbase = lane & 15;
    const int rbase = (lane >> 4) * 4;
    float xi[2][4], xj[2];
#pragma unroll
    for (int rt = 0; rt < 2; ++rt)
#pragma unroll
        for (int r = 0; r < 4; ++r)
            xi[rt][r] = x2s[ib + rt * 16 + rbase + r];
#pragma unroll
    for (int c = 0; c < 2; ++c)
        xj[c] = x2s[(w * 2 + c) * 16 + cbase];

#pragma unroll
    for (int rt = 0; rt < 2; ++rt)
#pragma unroll
        for (int c = 0; c < 2; ++c)
#pragma unroll
            for (int r = 0; r < 4; ++r) {
                float d2 = xi[rt][r] + xj[c] - 2.f * acc[rt][c][r];
                float dd = sqrtf(fmaxf(d2, 0.f) + 1e-12f);
                region[(rt * 16 + rbase + r) * PITCH + (w * 2 + c) * 16 + cbase] = dd;
            }
    __syncthreads();

    // ---- mining: wave-private (wave w owns anchors w*4..w*4+3) ----
    int llab[4];
#pragma unroll
    for (int ch = 0; ch < 4; ++ch) llab[ch] = label[p * M + ch * 64 + lane];

    for (int idx = lane; idx < NNEG; idx += 64) { fullS[w][idx] = 0.f; fullC[w][idx] = 0.f; }

    const unsigned long long lmask = (1ull << lane) - 1ull;
    float hardAcc = 0.f, rowSum = 0.f;

    for (int a = 0; a < 4; ++a) {
        const int ii = w * 4 + a;
        const int li = label[p * M + ib + ii];   // wave-uniform
        int runMatch = 0;
        float negmin = 3.4e38f;
        float ndv[4]; int nqv[4]; int nval[4];
#pragma unroll
        for (int ch = 0; ch < 4; ++ch) {
            const int j = ch * 64 + lane;
            float d = region[ii * PITCH + j];
            bool match = (llab[ch] == li);
            unsigned long long bal = __ballot(match);
            int posRank = runMatch + __popcll(bal & lmask);
            if (match) {
                if (posRank < NPOS) posbuf[w][posRank] = d;
                nval[ch] = 0; ndv[ch] = 0.f; nqv[ch] = 0;
            } else {
                ndv[ch] = d; nqv[ch] = j - posRank; nval[ch] = 1;
                negmin = fminf(negmin, d);
            }
            runMatch += __popcll(bal);
            rowSum += d;
        }
        asm volatile("s_waitcnt lgkmcnt(0)" ::: "memory");  // same-wave posbuf drain

        float maxpos = posbuf[w][0];
#pragma unroll
        for (int pp = 1; pp < NPOS; ++pp) maxpos = fmaxf(maxpos, posbuf[w][pp]);
#pragma unroll
        for (int off = 32; off >= 1; off >>= 1)
            negmin = fminf(negmin, __shfl_xor(negmin, off));
        hardAcc += fmaxf(MARG + maxpos - negmin, 0.f);

#pragma unroll
        for (int ch = 0; ch < 4; ++ch) {
            if (nval[ch]) {
                float dneg = ndv[ch]; int q = nqv[ch];
                float s = 0.f, cnt = 0.f;
#pragma unroll
                for (int pp = 0; pp < NPOS; ++pp) {
                    float v = MARG + posbuf[w][pp] - dneg;
                    if (v > 0.f) { s += v; cnt += 1.f; }
                }
                fullS[w][q] += s;   // per-wave private; q distinct per lane
                fullC[w][q] += cnt;
            }
        }
    }

#pragma unroll
    for (int off = 32; off >= 1; off >>= 1) rowSum += __shfl_xor(rowSum, off);
    if (lane == 0) { wred[w] = hardAcc; wred[8 + w] = rowSum; }
    __syncthreads();

    float* rec = recs + (size_t)swz * REC;
    if (t < NNEG) {
        float s = 0.f, c = 0.f;
#pragma unroll
        for (int v = 0; v < 8; ++v) { s += fullS[v][t]; c += fullC[v][t]; }
        rec[t] = s;
        rec[NNEG + t] = c;
    }
    if (t == 0) {
        float h = 0.f, ds = 0.f;
#pragma unroll
        for (int v = 0; v < 8; ++v) { h += wred[v]; ds += wred[8 + v]; }
        rec[496] = h;
        rec[497] = ds;
    }
}

// ======================= finalize =======================
__global__ __launch_bounds__(256) void k_fin1(const float* __restrict__ recs,
                                              float* __restrict__ out,
                                              float* __restrict__ wsP)
{
    const int p = blockIdx.x;
    const int t = threadIdx.x;
    if (t < NNEG) {
        float s = 0.f, c = 0.f;
        for (int a = 0; a < 8; ++a) {
            const float* rec = recs + (size_t)(p * 8 + a) * REC;
            s += rec[t];
            c += rec[NNEG + t];
        }
        out[p * NNEG + t]          = s / (c + 1e-6f);
        out[OFF_FN + p * NNEG + t] = c;
    }
    if (t == 0) {
        float h = 0.f, ds = 0.f;
        for (int a = 0; a < 8; ++a) {
            const float* rec = recs + (size_t)(p * 8 + a) * REC;
            h  += rec[496];
            ds += rec[497];
        }
        out[OFF_HARD + p] = h * (1.0f / 256.0f);
        wsP[p] = ds;
    }
}

__global__ void k_fin2(const float* __restrict__ wsP, float* __restrict__ out)
{
    int t = threadIdx.x;
    float v = (t < NPART) ? wsP[t] : 0.f;
#pragma unroll
    for (int off = 32; off >= 1; off >>= 1) v += __shfl_xor(v, off);
    if (t == 0) out[OFF_MD] = v / (float)((size_t)NPART * M * M);
}

// ======================= fallback: proven round-1 fused path =======================
__global__ __launch_bounds__(256) void fb_main(
    const float* __restrict__ F, const int* __restrict__ label, float* __restrict__ ws)
{
    __shared__ __align__(16) float region[256 * 36];
    __shared__ float x2s[M];
    __shared__ int   lab[M];
    __shared__ float posbuf[4][NPOS];
    __shared__ float fullS[4][NNEG];
    __shared__ float fullC[4][NNEG];
    __shared__ float wred[8];

    const int bx = blockIdx.x;
    const int p  = bx >> 3;
    const int ib = (bx & 7) * 32;
    const int t  = threadIdx.x;

    lab[t] = label[p * M + t];
    for (int idx = t; idx < 4 * NNEG; idx += 256) {
        (&fullS[0][0])[idx] = 0.f;
        (&fullC[0][0])[idx] = 0.f;
    }
    __syncthreads();

    const float4* Fv = (const float4*)(F + (size_t)p * (M * DD));

    float acc[4][8];
#pragma unroll
    for (int r = 0; r < 4; ++r)
#pragma unroll
        for (int c = 0; c < 8; ++c) acc[r][c] = 0.f;

    float x2loc = 0.f;
    const int tc = t & 31;
    const int tg = t >> 5;

    for (int kt = 0; kt < 8; ++kt) {
#pragma unroll
        for (int w = 0; w < 8; ++w) {
            int ch = w * 256 + t;
            int r  = ch >> 3;
            int q  = ch & 7;
            float4 v = Fv[r * 64 + kt * 8 + q];
            float* dst = &region[r * 36 + q * 4];
            dst[0] = v.x; dst[1] = v.y; dst[2] = v.z; dst[3] = v.w;
        }
        __syncthreads();
#pragma unroll
        for (int k4 = 0; k4 < 8; ++k4) {
            float4 b = *(const float4*)&region[t * 36 + k4 * 4];
            x2loc += b.x * b.x + b.y * b.y + b.z * b.z + b.w * b.w;
        }
#pragma unroll
        for (int k4 = 0; k4 < 8; ++k4) {
            float4 a4[4], b4[8];
#pragma unroll
            for (int r = 0; r < 4; ++r)
                a4[r] = *(const float4*)&region[(ib + tg * 4 + r) * 36 + k4 * 4];
#pragma unroll
            for (int c = 0; c < 8; ++c)
                b4[c] = *(const float4*)&region[(tc + 32 * c) * 36 + k4 * 4];
#pragma unroll
            for (int r = 0; r < 4; ++r)
#pragma unroll
                for (int c = 0; c < 8; ++c)
                    acc[r][c] += a4[r].x * b4[c].x + a4[r].y * b4[c].y +
                                 a4[r].z * b4[c].z + a4[r].w * b4[c].w;
        }
        __syncthreads();
    }

    x2s[t] = x2loc;
    __syncthreads();

#pragma unroll
    for (int r = 0; r < 4; ++r) {
        int ii = tg * 4 + r;
        float xi = x2s[ib + ii];
#pragma unroll
        for (int c = 0; c < 8; ++c) {
            int j = tc + 32 * c;
            float d2 = xi + x2s[j] - 2.f * acc[r][c];
            region[ii * M + j] = sqrtf(fmaxf(d2, 0.f) + 1e-12f);
        }
    }
    __syncthreads();

    const int lane = t & 63;
    const int w    = t >> 6;
    const unsigned long long lmask = (1ull << lane) - 1ull;

    float hardAcc = 0.f;
    float rowSum  = 0.f;

    for (int a = 0; a < 8; ++a) {
        int ii = w * 8 + a;
        int li = lab[ib + ii];
        int runMatch = 0;
        float negmin = 3.4e38f;
        float ndv[4]; int nqv[4]; int nval[4];
#pragma unroll
        for (int ch = 0; ch < 4; ++ch) {
            int j = ch * 64 + lane;
            float d = region[ii * M + j];
            bool match = (lab[j] == li);
            unsigned long long bal = __ballot(match);
            int prefix  = __popcll(bal & lmask);
            int posRank = runMatch + prefix;
            if (match) {
                if (posRank < NPOS) posbuf[w][posRank] = d;
                nval[ch] = 0; ndv[ch] = 0.f; nqv[ch] = 0;
            } else {
                ndv[ch] = d; nqv[ch] = j - posRank; nval[ch] = 1;
                negmin = fminf(negmin, d);
            }
            runMatch += __popcll(bal);
            rowSum += d;
        }
        __syncthreads();

        float maxpos = posbuf[w][0];
#pragma unroll
        for (int pp = 1; pp < NPOS; ++pp) maxpos = fmaxf(maxpos, posbuf[w][pp]);
#pragma unroll
        for (int off = 32; off >= 1; off >>= 1)
            negmin = fminf(negmin, __shfl_xor(negmin, off));
        hardAcc += fmaxf(MARG + maxpos - negmin, 0.f);

#pragma unroll
        for (int ch = 0; ch < 4; ++ch) {
            if (nval[ch]) {
                float dneg = ndv[ch]; int q = nqv[ch];
                float s = 0.f, cnt = 0.f;
#pragma unroll
                for (int pp = 0; pp < NPOS; ++pp) {
                    float v = MARG + posbuf[w][pp] - dneg;
                    if (v > 0.f) { s += v; cnt += 1.f; }
                }
                fullS[w][q] += s;
                fullC[w][q] += cnt;
            }
        }
        __syncthreads();
    }

#pragma unroll
    for (int off = 32; off >= 1; off >>= 1) rowSum += __shfl_xor(rowSum, off);
    if (lane == 0) { wred[w] = hardAcc; wred[4 + w] = rowSum; }
    __syncthreads();

    float* rec = ws + (size_t)bx * REC;
    if (t < NNEG) {
        float s = fullS[0][t] + fullS[1][t] + fullS[2][t] + fullS[3][t];
        float c = fullC[0][t] + fullC[1][t] + fullC[2][t] + fullC[3][t];
        rec[t] = s;
        rec[NNEG + t] = c;
    }
    if (t == 0) {
        rec[496] = wred[0] + wred[1] + wred[2] + wred[3];
        rec[497] = wred[4] + wred[5] + wred[6] + wred[7];
    }
}

// ======================= launch =======================
extern "C" void kernel_launch(void* const* d_in, const int* in_sizes, int n_in,
                              void* d_out, int out_size, void* d_ws, size_t ws_size,
                              hipStream_t stream)
{
    const float* F     = (const float*)d_in[0];
    const int*   label = (const int*)d_in[1];
    float*       ws    = (float*)d_ws;
    float*       out   = (float*)d_out;
    float*       recs  = ws + R0;
    float*       wsP   = ws + P0;

    if (ws_size >= WS_NEED) {
        k_all <<<dim3(496),   dim3(512), 0, stream>>>(F, label, recs);
        k_fin1<<<dim3(NPART), dim3(256), 0, stream>>>(recs, out, wsP);
        k_fin2<<<dim3(1),     dim3(64),  0, stream>>>(wsP, out);
    } else {
        fb_main<<<dim3(496),  dim3(256), 0, stream>>>(F, label, recs);
        k_fin1<<<dim3(NPART), dim3(256), 0, stream>>>(recs, out, wsP);
        k_fin2<<<dim3(1),     dim3(64),  0, stream>>>(wsP, out);
    }
}

// Round 8
// 43.845 us; speedup vs baseline: 1.1957x; 1.1957x over previous
//
#include <hip/hip_runtime.h>

#define NPART 62
#define M     256
#define DD    256
#define NPOS  8
#define NNEG  248
#define MARG  0.2f
#define REC   512

// ---- ws layout (float units) ----
#define FRAG_F 4063232                    // Ffrag: 8,126,464 halfs
#define X0     FRAG_F                     // x2 (62*256 floats)
#define R0     (X0 + NPART * M)           // recs (496*REC; main uses 248)
#define P0     (R0 + 496 * REC)           // per-part dist sums (62)
#define WS_NEED ((size_t)(P0 + NPART) * 4)

#define OFF_HARD 15376
#define OFF_MD   15438
#define OFF_FN   15439

typedef _Float16 f16x8 __attribute__((ext_vector_type(8)));
typedef float    f32x4 __attribute__((ext_vector_type(4)));

// ======================= split kernel: fp32 -> frag-layout fp16 hi/lo + x2 =======================
// Ffrag half-index: ((((p*8+s)*16 + tile)*2 + h)*64 + l)*8 + j
//   s = k>>5, g = (k>>3)&3, j = k&7, tile = row>>4, l = (row&15) + 16*g
__global__ __launch_bounds__(256) void k_split(const float* __restrict__ F,
                                               _Float16* __restrict__ Ffrag,
                                               float* __restrict__ x2g)
{
    const int b   = blockIdx.x;          // 992 = 62 parts * 16 tiles
    const int p   = b >> 4;
    const int t16 = b & 15;
    const int t   = threadIdx.x;
    const int row16 = t >> 4;            // row within tile
    const int kc    = t & 15;            // 16-k chunk

    const int row = t16 * 16 + row16;
    const float4* src = (const float4*)(F + ((size_t)(p * M + row) * DD) + kc * 16);

    float v[16];
#pragma unroll
    for (int i = 0; i < 4; ++i) {
        float4 q = src[i];
        v[i * 4 + 0] = q.x; v[i * 4 + 1] = q.y; v[i * 4 + 2] = q.z; v[i * 4 + 3] = q.w;
    }

    float s2 = 0.f;
#pragma unroll
    for (int i = 0; i < 16; ++i) s2 += v[i] * v[i];
    s2 += __shfl_xor(s2, 1);
    s2 += __shfl_xor(s2, 2);
    s2 += __shfl_xor(s2, 4);
    s2 += __shfl_xor(s2, 8);
    if (kc == 0) x2g[p * M + row] = s2;

#pragma unroll
    for (int b2 = 0; b2 < 2; ++b2) {
        const int o = kc * 2 + b2;       // global k-octet
        const int s = o >> 2;
        const int g = o & 3;
        const int l = row16 + 16 * g;
        f16x8 hv, lv;
#pragma unroll
        for (int j = 0; j < 8; ++j) {
            float x = v[b2 * 8 + j];
            _Float16 h = (_Float16)x;
            hv[j] = h;
            lv[j] = (_Float16)(x - (float)h);
        }
        size_t base = ((((size_t)(p * 8 + s) * 16 + t16) * 2 + 0) * 64 + l) * 8;
        *(f16x8*)(Ffrag + base)         = hv;   // h=0
        *(f16x8*)(Ffrag + base + 512)   = lv;   // h=1
    }
}

// ======================= MFMA dist + mining, 64-row blocks =======================
#define PITCH 258
__global__ __launch_bounds__(1024) void k_dist(const _Float16* __restrict__ Ffrag,
                                               const float* __restrict__ x2g,
                                               const int* __restrict__ label,
                                               float* __restrict__ recs)
{
    __shared__ __align__(16) float region[64 * PITCH];   // 66,048 B
    __shared__ float fullS[16][NNEG];
    __shared__ float fullC[16][NNEG];
    __shared__ float posbuf[16][NPOS];
    __shared__ float wred[32];

    const int bxr = blockIdx.x;                       // 248 = 8 XCD * 31
    const int swz = (bxr & 7) * 31 + (bxr >> 3);      // bijective; part's 4 tiles same-XCD
    const int p   = swz >> 2;
    const int rt4 = swz & 3;
    const int ib  = rt4 * 64;                         // anchor base
    const int a0  = rt4 * 4;                          // first A row-tile (of 16)
    const int t   = threadIdx.x;
    const int lane = t & 63;
    const int w    = t >> 6;                          // wave 0..15 = B col-tile

    const _Float16* Pbase = Ffrag + (size_t)p * 131072 + lane * 8;

    f32x4 acc[4];
#pragma unroll
    for (int rt = 0; rt < 4; ++rt) acc[rt] = (f32x4){0.f, 0.f, 0.f, 0.f};

    f16x8 cAh[4], cAl[4], cB[2], nAh[4], nB[2];

    auto LH = [&](int s, f16x8 (&Ah)[4], f16x8 (&B)[2]) {
        const _Float16* SB = Pbase + s * 16384;
#pragma unroll
        for (int rt = 0; rt < 4; ++rt)
            Ah[rt] = *(const f16x8*)(SB + ((a0 + rt) * 2 + 0) * 512);
#pragma unroll
        for (int h = 0; h < 2; ++h)
            B[h] = *(const f16x8*)(SB + (w * 2 + h) * 512);
    };
    auto LL = [&](int s, f16x8 (&Al)[4]) {
        const _Float16* SB = Pbase + s * 16384;
#pragma unroll
        for (int rt = 0; rt < 4; ++rt)
            Al[rt] = *(const f16x8*)(SB + ((a0 + rt) * 2 + 1) * 512);
    };

    LH(0, cAh, cB);
    LL(0, cAl);
#pragma unroll
    for (int s = 0; s < 8; ++s) {
        if (s < 7) LH(s + 1, nAh, nB);               // prefetch next hi-set
#pragma unroll
        for (int rt = 0; rt < 4; ++rt)               // hi*hi
            acc[rt] = __builtin_amdgcn_mfma_f32_16x16x32_f16(cAh[rt], cB[0], acc[rt], 0, 0, 0);
#pragma unroll
        for (int rt = 0; rt < 4; ++rt)               // hi*lo
            acc[rt] = __builtin_amdgcn_mfma_f32_16x16x32_f16(cAh[rt], cB[1], acc[rt], 0, 0, 0);
#pragma unroll
        for (int rt = 0; rt < 4; ++rt)               // lo*hi
            acc[rt] = __builtin_amdgcn_mfma_f32_16x16x32_f16(cAl[rt], cB[0], acc[rt], 0, 0, 0);
        if (s < 7) {
            LL(s + 1, cAl);                          // reuse regs after lo*hi consumed them
#pragma unroll
            for (int rt = 0; rt < 4; ++rt) cAh[rt] = nAh[rt];
            cB[0] = nB[0]; cB[1] = nB[1];
        }
    }

    // ---- epilogue: dist -> LDS (C/D layout: col=lane&15, row=(lane>>4)*4+r) ----
    const int cbase = lane & 15;
    const int rbase = (lane >> 4) * 4;
    const float xj = x2g[p * M + w * 16 + cbase];
#pragma unroll
    for (int rt = 0; rt < 4; ++rt)
#pragma unroll
        for (int r = 0; r < 4; ++r) {
            float xi = x2g[p * M + ib + rt * 16 + rbase + r];
            float d2 = xi + xj - 2.f * acc[rt][r];
            float dd = sqrtf(fmaxf(d2, 0.f) + 1e-12f);
            region[(rt * 16 + rbase + r) * PITCH + w * 16 + cbase] = dd;
        }
    __syncthreads();

    // ---- mining: wave-private (wave w owns anchors w*4..w*4+3 of this 64-row tile) ----
    int llab[4];
#pragma unroll
    for (int ch = 0; ch < 4; ++ch) llab[ch] = label[p * M + ch * 64 + lane];

    for (int idx = lane; idx < NNEG; idx += 64) { fullS[w][idx] = 0.f; fullC[w][idx] = 0.f; }

    const unsigned long long lmask = (1ull << lane) - 1ull;
    float hardAcc = 0.f, rowSum = 0.f;

    for (int a = 0; a < 4; ++a) {
        const int ii = w * 4 + a;
        const int li = label[p * M + ib + ii];   // wave-uniform
        int runMatch = 0;
        float negmin = 3.4e38f;
        float ndv[4]; int nqv[4]; int nval[4];
#pragma unroll
        for (int ch = 0; ch < 4; ++ch) {
            const int j = ch * 64 + lane;
            float d = region[ii * PITCH + j];
            bool match = (llab[ch] == li);
            unsigned long long bal = __ballot(match);
            int posRank = runMatch + __popcll(bal & lmask);
            if (match) {
                if (posRank < NPOS) posbuf[w][posRank] = d;
                nval[ch] = 0; ndv[ch] = 0.f; nqv[ch] = 0;
            } else {
                ndv[ch] = d; nqv[ch] = j - posRank; nval[ch] = 1;
                negmin = fminf(negmin, d);
            }
            runMatch += __popcll(bal);
            rowSum += d;
        }
        asm volatile("s_waitcnt lgkmcnt(0)" ::: "memory");  // same-wave posbuf drain

        float maxpos = posbuf[w][0];
#pragma unroll
        for (int pp = 1; pp < NPOS; ++pp) maxpos = fmaxf(maxpos, posbuf[w][pp]);
#pragma unroll
        for (int off = 32; off >= 1; off >>= 1)
            negmin = fminf(negmin, __shfl_xor(negmin, off));
        hardAcc += fmaxf(MARG + maxpos - negmin, 0.f);

#pragma unroll
        for (int ch = 0; ch < 4; ++ch) {
            if (nval[ch]) {
                float dneg = ndv[ch]; int q = nqv[ch];
                float s = 0.f, cnt = 0.f;
#pragma unroll
                for (int pp = 0; pp < NPOS; ++pp) {
                    float v = MARG + posbuf[w][pp] - dneg;
                    if (v > 0.f) { s += v; cnt += 1.f; }
                }
                fullS[w][q] += s;   // per-wave private; q distinct per lane
                fullC[w][q] += cnt;
            }
        }
    }

#pragma unroll
    for (int off = 32; off >= 1; off >>= 1) rowSum += __shfl_xor(rowSum, off);
    if (lane == 0) { wred[w] = hardAcc; wred[16 + w] = rowSum; }
    __syncthreads();

    float* rec = recs + (size_t)swz * REC;
    if (t < NNEG) {
        float s = 0.f, c = 0.f;
#pragma unroll
        for (int v = 0; v < 16; ++v) { s += fullS[v][t]; c += fullC[v][t]; }
        rec[t] = s;
        rec[NNEG + t] = c;
    }
    if (t == 0) {
        float h = 0.f, ds = 0.f;
#pragma unroll
        for (int v = 0; v < 16; ++v) { h += wred[v]; ds += wred[16 + v]; }
        rec[496] = h;
        rec[497] = ds;
    }
}

// ======================= finalize (main: 4 recs/part) =======================
__global__ __launch_bounds__(256) void k_fin1(const float* __restrict__ recs,
                                              float* __restrict__ out,
                                              float* __restrict__ wsP)
{
    const int p = blockIdx.x;
    const int t = threadIdx.x;
    if (t < NNEG) {
        float s = 0.f, c = 0.f;
        for (int a = 0; a < 4; ++a) {
            const float* rec = recs + (size_t)(p * 4 + a) * REC;
            s += rec[t];
            c += rec[NNEG + t];
        }
        out[p * NNEG + t]          = s / (c + 1e-6f);
        out[OFF_FN + p * NNEG + t] = c;
    }
    if (t == 0) {
        float h = 0.f, ds = 0.f;
        for (int a = 0; a < 4; ++a) {
            const float* rec = recs + (size_t)(p * 4 + a) * REC;
            h  += rec[496];
            ds += rec[497];
        }
        out[OFF_HARD + p] = h * (1.0f / 256.0f);
        wsP[p] = ds;
    }
}

__global__ void k_fin2(const float* __restrict__ wsP, float* __restrict__ out)
{
    int t = threadIdx.x;
    float v = (t < NPART) ? wsP[t] : 0.f;
#pragma unroll
    for (int off = 32; off >= 1; off >>= 1) v += __shfl_xor(v, off);
    if (t == 0) out[OFF_MD] = v / (float)((size_t)NPART * M * M);
}

// ======================= fallback: proven round-1 fused path =======================
__global__ __launch_bounds__(256) void fb_main(
    const float* __restrict__ F, const int* __restrict__ label, float* __restrict__ ws)
{
    __shared__ __align__(16) float region[256 * 36];
    __shared__ float x2s[M];
    __shared__ int   lab[M];
    __shared__ float posbuf[4][NPOS];
    __shared__ float fullS[4][NNEG];
    __shared__ float fullC[4][NNEG];
    __shared__ float wred[8];

    const int bx = blockIdx.x;
    const int p  = bx >> 3;
    const int ib = (bx & 7) * 32;
    const int t  = threadIdx.x;

    lab[t] = label[p * M + t];
    for (int idx = t; idx < 4 * NNEG; idx += 256) {
        (&fullS[0][0])[idx] = 0.f;
        (&fullC[0][0])[idx] = 0.f;
    }
    __syncthreads();

    const float4* Fv = (const float4*)(F + (size_t)p * (M * DD));

    float acc[4][8];
#pragma unroll
    for (int r = 0; r < 4; ++r)
#pragma unroll
        for (int c = 0; c < 8; ++c) acc[r][c] = 0.f;

    float x2loc = 0.f;
    const int tc = t & 31;
    const int tg = t >> 5;

    for (int kt = 0; kt < 8; ++kt) {
#pragma unroll
        for (int w = 0; w < 8; ++w) {
            int ch = w * 256 + t;
            int r  = ch >> 3;
            int q  = ch & 7;
            float4 v = Fv[r * 64 + kt * 8 + q];
            float* dst = &region[r * 36 + q * 4];
            dst[0] = v.x; dst[1] = v.y; dst[2] = v.z; dst[3] = v.w;
        }
        __syncthreads();
#pragma unroll
        for (int k4 = 0; k4 < 8; ++k4) {
            float4 b = *(const float4*)&region[t * 36 + k4 * 4];
            x2loc += b.x * b.x + b.y * b.y + b.z * b.z + b.w * b.w;
        }
#pragma unroll
        for (int k4 = 0; k4 < 8; ++k4) {
            float4 a4[4], b4[8];
#pragma unroll
            for (int r = 0; r < 4; ++r)
                a4[r] = *(const float4*)&region[(ib + tg * 4 + r) * 36 + k4 * 4];
#pragma unroll
            for (int c = 0; c < 8; ++c)
                b4[c] = *(const float4*)&region[(tc + 32 * c) * 36 + k4 * 4];
#pragma unroll
            for (int r = 0; r < 4; ++r)
#pragma unroll
                for (int c = 0; c < 8; ++c)
                    acc[r][c] += a4[r].x * b4[c].x + a4[r].y * b4[c].y +
                                 a4[r].z * b4[c].z + a4[r].w * b4[c].w;
        }
        __syncthreads();
    }

    x2s[t] = x2loc;
    __syncthreads();

#pragma unroll
    for (int r = 0; r < 4; ++r) {
        int ii = tg * 4 + r;
        float xi = x2s[ib + ii];
#pragma unroll
        for (int c = 0; c < 8; ++c) {
            int j = tc + 32 * c;
            float d2 = xi + x2s[j] - 2.f * acc[r][c];
            region[ii * M + j] = sqrtf(fmaxf(d2, 0.f) + 1e-12f);
        }
    }
    __syncthreads();

    const int lane = t & 63;
    const int w    = t >> 6;
    const unsigned long long lmask = (1ull << lane) - 1ull;

    float hardAcc = 0.f;
    float rowSum  = 0.f;

    for (int a = 0; a < 8; ++a) {
        int ii = w * 8 + a;
        int li = lab[ib + ii];
        int runMatch = 0;
        float negmin = 3.4e38f;
        float ndv[4]; int nqv[4]; int nval[4];
#pragma unroll
        for (int ch = 0; ch < 4; ++ch) {
            int j = ch * 64 + lane;
            float d = region[ii * M + j];
            bool match = (lab[j] == li);
            unsigned long long bal = __ballot(match);
            int prefix  = __popcll(bal & lmask);
            int posRank = runMatch + prefix;
            if (match) {
                if (posRank < NPOS) posbuf[w][posRank] = d;
                nval[ch] = 0; ndv[ch] = 0.f; nqv[ch] = 0;
            } else {
                ndv[ch] = d; nqv[ch] = j - posRank; nval[ch] = 1;
                negmin = fminf(negmin, d);
            }
            runMatch += __popcll(bal);
            rowSum += d;
        }
        __syncthreads();

        float maxpos = posbuf[w][0];
#pragma unroll
        for (int pp = 1; pp < NPOS; ++pp) maxpos = fmaxf(maxpos, posbuf[w][pp]);
#pragma unroll
        for (int off = 32; off >= 1; off >>= 1)
            negmin = fminf(negmin, __shfl_xor(negmin, off));
        hardAcc += fmaxf(MARG + maxpos - negmin, 0.f);

#pragma unroll
        for (int ch = 0; ch < 4; ++ch) {
            if (nval[ch]) {
                float dneg = ndv[ch]; int q = nqv[ch];
                float s = 0.f, cnt = 0.f;
#pragma unroll
                for (int pp = 0; pp < NPOS; ++pp) {
                    float v = MARG + posbuf[w][pp] - dneg;
                    if (v > 0.f) { s += v; cnt += 1.f; }
                }
                fullS[w][q] += s;
                fullC[w][q] += cnt;
            }
        }
        __syncthreads();
    }

#pragma unroll
    for (int off = 32; off >= 1; off >>= 1) rowSum += __shfl_xor(rowSum, off);
    if (lane == 0) { wred[w] = hardAcc; wred[4 + w] = rowSum; }
    __syncthreads();

    float* rec = ws + (size_t)bx * REC;
    if (t < NNEG) {
        float s = fullS[0][t] + fullS[1][t] + fullS[2][t] + fullS[3][t];
        float c = fullC[0][t] + fullC[1][t] + fullC[2][t] + fullC[3][t];
        rec[t] = s;
        rec[NNEG + t] = c;
    }
    if (t == 0) {
        rec[496] = wred[0] + wred[1] + wred[2] + wred[3];
        rec[497] = wred[4] + wred[5] + wred[6] + wred[7];
    }
}

__global__ __launch_bounds__(256) void fb_fin1(const float* __restrict__ recs,
                                               float* __restrict__ out,
                                               float* __restrict__ wsP)
{
    const int p = blockIdx.x;
    const int t = threadIdx.x;
    if (t < NNEG) {
        float s = 0.f, c = 0.f;
        for (int a = 0; a < 8; ++a) {
            const float* rec = recs + (size_t)(p * 8 + a) * REC;
            s += rec[t];
            c += rec[NNEG + t];
        }
        out[p * NNEG + t]          = s / (c + 1e-6f);
        out[OFF_FN + p * NNEG + t] = c;
    }
    if (t == 0) {
        float h = 0.f, ds = 0.f;
        for (int a = 0; a < 8; ++a) {
            const float* rec = recs + (size_t)(p * 8 + a) * REC;
            h  += rec[496];
            ds += rec[497];
        }
        out[OFF_HARD + p] = h * (1.0f / 256.0f);
        wsP[p] = ds;
    }
}

// ======================= launch =======================
extern "C" void kernel_launch(void* const* d_in, const int* in_sizes, int n_in,
                              void* d_out, int out_size, void* d_ws, size_t ws_size,
                              hipStream_t stream)
{
    const float* F     = (const float*)d_in[0];
    const int*   label = (const int*)d_in[1];
    float*       ws    = (float*)d_ws;
    float*       out   = (float*)d_out;

    if (ws_size >= WS_NEED) {
        _Float16* Ffrag = (_Float16*)ws;
        float*    x2g   = ws + X0;
        float*    recs  = ws + R0;
        float*    wsP   = ws + P0;
        k_split<<<dim3(992),   dim3(256),  0, stream>>>(F, Ffrag, x2g);
        k_dist <<<dim3(248),   dim3(1024), 0, stream>>>(Ffrag, x2g, label, recs);
        k_fin1 <<<dim3(NPART), dim3(256),  0, stream>>>(recs, out, wsP);
        k_fin2 <<<dim3(1),     dim3(64),   0, stream>>>(wsP, out);
    } else {
        float* recs = ws;
        float* wsP  = ws + 496 * REC;
        fb_main<<<dim3(496),   dim3(256), 0, stream>>>(F, label, recs);
        fb_fin1<<<dim3(NPART), dim3(256), 0, stream>>>(recs, out, wsP);
        k_fin2 <<<dim3(1),     dim3(64),  0, stream>>>(wsP, out);
    }
}

// Round 9
// 28.179 us; speedup vs baseline: 1.8604x; 1.5559x over previous
//
#include <hip/hip_runtime.h>

#define NPART 62
#define M     256
#define DD    256
#define NPOS  8
#define NNEG  248
#define MARG  0.2f
#define REC   512

// ---- ws layout (float units): recs + per-part sums only ----
#define R0      0
#define P0      (496 * REC)
#define WS_NEED ((size_t)(P0 + NPART) * 4)

#define OFF_HARD 15376
#define OFF_MD   15438
#define OFF_FN   15439

typedef _Float16 f16x8 __attribute__((ext_vector_type(8)));
typedef float    f32x4 __attribute__((ext_vector_type(4)));

#define PITCH 258

// ======================= fused convert + staged MFMA dist + mining =======================
// 248 blocks (8 XCD x 31), 1024 threads. Block = (part p, 64-row tile rt4).
__global__ __launch_bounds__(1024) void k_all(const float* __restrict__ F,
                                              const int* __restrict__ label,
                                              float* __restrict__ recs)
{
    // stage: 2 x 32KB fragment-layout slabs; later overlaid by dist[64][PITCH] (66,048 B)
    __shared__ __align__(16) char smem[64 * PITCH * 4];
    __shared__ float x2s[M];
    __shared__ float fullS[16][NNEG];
    __shared__ float fullC[16][NNEG];
    __shared__ float posbuf[16][NPOS];
    __shared__ float wred[32];

    const int bxr = blockIdx.x;                       // 248 = 8 XCD * 31
    const int swz = (bxr & 7) * 31 + (bxr >> 3);      // bijective; part's 4 tiles same-XCD
    const int p   = swz >> 2;
    const int rt4 = swz & 3;
    const int ib  = rt4 * 64;                         // anchor base (global row)
    const int a0  = rt4 * 4;                          // first A row-tile (of 16)
    const int t   = threadIdx.x;
    const int lane = t & 63;
    const int w    = t >> 6;                          // wave 0..15 = B col-tile

    const float* Fp = F + (size_t)p * (M * DD);

    // staging role: thread t covers (row = t>>2, k-octet = t&3) of each 32-k slab
    const int srow = t >> 2;
    const int soct = t & 3;
    const int stile = srow >> 4;
    // frag-halfs offset within a 16384-half slab: ((tile*2+h)*64 + (row&15)+16*oct)*8
    const int whalf_hi = ((stile * 2 + 0) * 64 + (srow & 15) + 16 * soct) * 8;
    const int whalf_lo = ((stile * 2 + 1) * 64 + (srow & 15) + 16 * soct) * 8;
    const float* gsrc = Fp + srow * DD + soct * 8;

    _Float16* stage[2] = { (_Float16*)smem, (_Float16*)(smem + 32768) };

    f32x4 acc[4];
#pragma unroll
    for (int rt = 0; rt < 4; ++rt) acc[rt] = (f32x4){0.f, 0.f, 0.f, 0.f};

    float x2p = 0.f;
    float4 v0, v1, n0, n1;

    // prologue: slab 0
    v0 = *(const float4*)(gsrc + 0);
    v1 = *(const float4*)(gsrc + 4);
    {
        float x[8] = {v0.x, v0.y, v0.z, v0.w, v1.x, v1.y, v1.z, v1.w};
        f16x8 hv, lv;
#pragma unroll
        for (int j = 0; j < 8; ++j) {
            x2p += x[j] * x[j];
            _Float16 h = (_Float16)x[j];
            hv[j] = h;
            lv[j] = (_Float16)(x[j] - (float)h);
        }
        *(f16x8*)(stage[0] + whalf_hi) = hv;
        *(f16x8*)(stage[0] + whalf_lo) = lv;
    }
    __syncthreads();

#pragma unroll
    for (int s = 0; s < 8; ++s) {
        if (s < 7) {                                   // issue next-slab loads early
            n0 = *(const float4*)(gsrc + (s + 1) * 32 + 0);
            n1 = *(const float4*)(gsrc + (s + 1) * 32 + 4);
        }
        // compute slab s from stage[s&1]
        const _Float16* SB = stage[s & 1];
        {
            f16x8 Bh = *(const f16x8*)(SB + ((w * 2 + 0) * 64 + lane) * 8);
            f16x8 Bl = *(const f16x8*)(SB + ((w * 2 + 1) * 64 + lane) * 8);
#pragma unroll
            for (int rt = 0; rt < 4; ++rt) {
                f16x8 Ah = *(const f16x8*)(SB + (((a0 + rt) * 2 + 0) * 64 + lane) * 8);
                f16x8 Al = *(const f16x8*)(SB + (((a0 + rt) * 2 + 1) * 64 + lane) * 8);
                acc[rt] = __builtin_amdgcn_mfma_f32_16x16x32_f16(Ah, Bh, acc[rt], 0, 0, 0);
                acc[rt] = __builtin_amdgcn_mfma_f32_16x16x32_f16(Ah, Bl, acc[rt], 0, 0, 0);
                acc[rt] = __builtin_amdgcn_mfma_f32_16x16x32_f16(Al, Bh, acc[rt], 0, 0, 0);
            }
        }
        if (s < 7) {                                   // convert + write slab s+1 (other buffer)
            float x[8] = {n0.x, n0.y, n0.z, n0.w, n1.x, n1.y, n1.z, n1.w};
            f16x8 hv, lv;
#pragma unroll
            for (int j = 0; j < 8; ++j) {
                x2p += x[j] * x[j];
                _Float16 h = (_Float16)x[j];
                hv[j] = h;
                lv[j] = (_Float16)(x[j] - (float)h);
            }
            _Float16* SW = stage[(s + 1) & 1];
            *(f16x8*)(SW + whalf_hi) = hv;
            *(f16x8*)(SW + whalf_lo) = lv;
            __syncthreads();                           // writes visible before next compute
        }
    }

    // ---- x2: reduce over the 4 octets (lanes differing in bits 0..1), publish ----
    x2p += __shfl_xor(x2p, 1);
    x2p += __shfl_xor(x2p, 2);
    if ((lane & 3) == 0) x2s[srow] = x2p;
    __syncthreads();   // x2s ready AND all waves done with stage buffers

    // ---- epilogue: dist -> LDS region (overlays stage) ----
    float* region = (float*)smem;
    const int cbase = lane & 15;
    const int rbase = (lane >> 4) * 4;
    const float xj = x2s[w * 16 + cbase];
#pragma unroll
    for (int rt = 0; rt < 4; ++rt)
#pragma unroll
        for (int r = 0; r < 4; ++r) {
            float xi = x2s[ib + rt * 16 + rbase + r];
            float d2 = xi + xj - 2.f * acc[rt][r];
            float dd = sqrtf(fmaxf(d2, 0.f) + 1e-12f);
            region[(rt * 16 + rbase + r) * PITCH + w * 16 + cbase] = dd;
        }
    __syncthreads();

    // ---- mining: wave-private (wave w owns local anchors w*4..w*4+3) ----
    int llab[4];
#pragma unroll
    for (int ch = 0; ch < 4; ++ch) llab[ch] = label[p * M + ch * 64 + lane];

    for (int idx = lane; idx < NNEG; idx += 64) { fullS[w][idx] = 0.f; fullC[w][idx] = 0.f; }

    const unsigned long long lmask = (1ull << lane) - 1ull;
    float hardAcc = 0.f, rowSum = 0.f;

    for (int a = 0; a < 4; ++a) {
        const int ii = w * 4 + a;
        const int li = label[p * M + ib + ii];   // wave-uniform
        int runMatch = 0;
        float negmin = 3.4e38f;
        float ndv[4]; int nqv[4]; int nval[4];
#pragma unroll
        for (int ch = 0; ch < 4; ++ch) {
            const int j = ch * 64 + lane;
            float d = region[ii * PITCH + j];
            bool match = (llab[ch] == li);
            unsigned long long bal = __ballot(match);
            int posRank = runMatch + __popcll(bal & lmask);
            if (match) {
                if (posRank < NPOS) posbuf[w][posRank] = d;
                nval[ch] = 0; ndv[ch] = 0.f; nqv[ch] = 0;
            } else {
                ndv[ch] = d; nqv[ch] = j - posRank; nval[ch] = 1;
                negmin = fminf(negmin, d);
            }
            runMatch += __popcll(bal);
            rowSum += d;
        }
        asm volatile("s_waitcnt lgkmcnt(0)" ::: "memory");  // same-wave posbuf drain

        float maxpos = posbuf[w][0];
#pragma unroll
        for (int pp = 1; pp < NPOS; ++pp) maxpos = fmaxf(maxpos, posbuf[w][pp]);
#pragma unroll
        for (int off = 32; off >= 1; off >>= 1)
            negmin = fminf(negmin, __shfl_xor(negmin, off));
        hardAcc += fmaxf(MARG + maxpos - negmin, 0.f);

#pragma unroll
        for (int ch = 0; ch < 4; ++ch) {
            if (nval[ch]) {
                float dneg = ndv[ch]; int q = nqv[ch];
                float s = 0.f, cnt = 0.f;
#pragma unroll
                for (int pp = 0; pp < NPOS; ++pp) {
                    float v = MARG + posbuf[w][pp] - dneg;
                    if (v > 0.f) { s += v; cnt += 1.f; }
                }
                fullS[w][q] += s;   // per-wave private; q distinct per lane
                fullC[w][q] += cnt;
            }
        }
    }

#pragma unroll
    for (int off = 32; off >= 1; off >>= 1) rowSum += __shfl_xor(rowSum, off);
    if (lane == 0) { wred[w] = hardAcc; wred[16 + w] = rowSum; }
    __syncthreads();

    float* rec = recs + (size_t)swz * REC;
    if (t < NNEG) {
        float s = 0.f, c = 0.f;
#pragma unroll
        for (int v = 0; v < 16; ++v) { s += fullS[v][t]; c += fullC[v][t]; }
        rec[t] = s;
        rec[NNEG + t] = c;
    }
    if (t == 0) {
        float h = 0.f, ds = 0.f;
#pragma unroll
        for (int v = 0; v < 16; ++v) { h += wred[v]; ds += wred[16 + v]; }
        rec[496] = h;
        rec[497] = ds;
    }
}

// ======================= finalize (main: 4 recs/part) =======================
__global__ __launch_bounds__(256) void k_fin1(const float* __restrict__ recs,
                                              float* __restrict__ out,
                                              float* __restrict__ wsP)
{
    const int p = blockIdx.x;
    const int t = threadIdx.x;
    if (t < NNEG) {
        float s = 0.f, c = 0.f;
        for (int a = 0; a < 4; ++a) {
            const float* rec = recs + (size_t)(p * 4 + a) * REC;
            s += rec[t];
            c += rec[NNEG + t];
        }
        out[p * NNEG + t]          = s / (c + 1e-6f);
        out[OFF_FN + p * NNEG + t] = c;
    }
    if (t == 0) {
        float h = 0.f, ds = 0.f;
        for (int a = 0; a < 4; ++a) {
            const float* rec = recs + (size_t)(p * 4 + a) * REC;
            h  += rec[496];
            ds += rec[497];
        }
        out[OFF_HARD + p] = h * (1.0f / 256.0f);
        wsP[p] = ds;
    }
}

__global__ void k_fin2(const float* __restrict__ wsP, float* __restrict__ out)
{
    int t = threadIdx.x;
    float v = (t < NPART) ? wsP[t] : 0.f;
#pragma unroll
    for (int off = 32; off >= 1; off >>= 1) v += __shfl_xor(v, off);
    if (t == 0) out[OFF_MD] = v / (float)((size_t)NPART * M * M);
}

// ======================= fallback: proven round-1 fused path =======================
__global__ __launch_bounds__(256) void fb_main(
    const float* __restrict__ F, const int* __restrict__ label, float* __restrict__ ws)
{
    __shared__ __align__(16) float region[256 * 36];
    __shared__ float x2s[M];
    __shared__ int   lab[M];
    __shared__ float posbuf[4][NPOS];
    __shared__ float fullS[4][NNEG];
    __shared__ float fullC[4][NNEG];
    __shared__ float wred[8];

    const int bx = blockIdx.x;
    const int p  = bx >> 3;
    const int ib = (bx & 7) * 32;
    const int t  = threadIdx.x;

    lab[t] = label[p * M + t];
    for (int idx = t; idx < 4 * NNEG; idx += 256) {
        (&fullS[0][0])[idx] = 0.f;
        (&fullC[0][0])[idx] = 0.f;
    }
    __syncthreads();

    const float4* Fv = (const float4*)(F + (size_t)p * (M * DD));

    float acc[4][8];
#pragma unroll
    for (int r = 0; r < 4; ++r)
#pragma unroll
        for (int c = 0; c < 8; ++c) acc[r][c] = 0.f;

    float x2loc = 0.f;
    const int tc = t & 31;
    const int tg = t >> 5;

    for (int kt = 0; kt < 8; ++kt) {
#pragma unroll
        for (int w = 0; w < 8; ++w) {
            int ch = w * 256 + t;
            int r  = ch >> 3;
            int q  = ch & 7;
            float4 v = Fv[r * 64 + kt * 8 + q];
            float* dst = &region[r * 36 + q * 4];
            dst[0] = v.x; dst[1] = v.y; dst[2] = v.z; dst[3] = v.w;
        }
        __syncthreads();
#pragma unroll
        for (int k4 = 0; k4 < 8; ++k4) {
            float4 b = *(const float4*)&region[t * 36 + k4 * 4];
            x2loc += b.x * b.x + b.y * b.y + b.z * b.z + b.w * b.w;
        }
#pragma unroll
        for (int k4 = 0; k4 < 8; ++k4) {
            float4 a4[4], b4[8];
#pragma unroll
            for (int r = 0; r < 4; ++r)
                a4[r] = *(const float4*)&region[(ib + tg * 4 + r) * 36 + k4 * 4];
#pragma unroll
            for (int c = 0; c < 8; ++c)
                b4[c] = *(const float4*)&region[(tc + 32 * c) * 36 + k4 * 4];
#pragma unroll
            for (int r = 0; r < 4; ++r)
#pragma unroll
                for (int c = 0; c < 8; ++c)
                    acc[r][c] += a4[r].x * b4[c].x + a4[r].y * b4[c].y +
                                 a4[r].z * b4[c].z + a4[r].w * b4[c].w;
        }
        __syncthreads();
    }

    x2s[t] = x2loc;
    __syncthreads();

#pragma unroll
    for (int r = 0; r < 4; ++r) {
        int ii = tg * 4 + r;
        float xi = x2s[ib + ii];
#pragma unroll
        for (int c = 0; c < 8; ++c) {
            int j = tc + 32 * c;
            float d2 = xi + x2s[j] - 2.f * acc[r][c];
            region[ii * M + j] = sqrtf(fmaxf(d2, 0.f) + 1e-12f);
        }
    }
    __syncthreads();

    const int lane = t & 63;
    const int w    = t >> 6;
    const unsigned long long lmask = (1ull << lane) - 1ull;

    float hardAcc = 0.f;
    float rowSum  = 0.f;

    for (int a = 0; a < 8; ++a) {
        int ii = w * 8 + a;
        int li = lab[ib + ii];
        int runMatch = 0;
        float negmin = 3.4e38f;
        float ndv[4]; int nqv[4]; int nval[4];
#pragma unroll
        for (int ch = 0; ch < 4; ++ch) {
            int j = ch * 64 + lane;
            float d = region[ii * M + j];
            bool match = (lab[j] == li);
            unsigned long long bal = __ballot(match);
            int prefix  = __popcll(bal & lmask);
            int posRank = runMatch + prefix;
            if (match) {
                if (posRank < NPOS) posbuf[w][posRank] = d;
                nval[ch] = 0; ndv[ch] = 0.f; nqv[ch] = 0;
            } else {
                ndv[ch] = d; nqv[ch] = j - posRank; nval[ch] = 1;
                negmin = fminf(negmin, d);
            }
            runMatch += __popcll(bal);
            rowSum += d;
        }
        __syncthreads();

        float maxpos = posbuf[w][0];
#pragma unroll
        for (int pp = 1; pp < NPOS; ++pp) maxpos = fmaxf(maxpos, posbuf[w][pp]);
#pragma unroll
        for (int off = 32; off >= 1; off >>= 1)
            negmin = fminf(negmin, __shfl_xor(negmin, off));
        hardAcc += fmaxf(MARG + maxpos - negmin, 0.f);

#pragma unroll
        for (int ch = 0; ch < 4; ++ch) {
            if (nval[ch]) {
                float dneg = ndv[ch]; int q = nqv[ch];
                float s = 0.f, cnt = 0.f;
#pragma unroll
                for (int pp = 0; pp < NPOS; ++pp) {
                    float v = MARG + posbuf[w][pp] - dneg;
                    if (v > 0.f) { s += v; cnt += 1.f; }
                }
                fullS[w][q] += s;
                fullC[w][q] += cnt;
            }
        }
        __syncthreads();
    }

#pragma unroll
    for (int off = 32; off >= 1; off >>= 1) rowSum += __shfl_xor(rowSum, off);
    if (lane == 0) { wred[w] = hardAcc; wred[4 + w] = rowSum; }
    __syncthreads();

    float* rec = ws + (size_t)bx * REC;
    if (t < NNEG) {
        float s = fullS[0][t] + fullS[1][t] + fullS[2][t] + fullS[3][t];
        float c = fullC[0][t] + fullC[1][t] + fullC[2][t] + fullC[3][t];
        rec[t] = s;
        rec[NNEG + t] = c;
    }
    if (t == 0) {
        rec[496] = wred[0] + wred[1] + wred[2] + wred[3];
        rec[497] = wred[4] + wred[5] + wred[6] + wred[7];
    }
}

__global__ __launch_bounds__(256) void fb_fin1(const float* __restrict__ recs,
                                               float* __restrict__ out,
                                               float* __restrict__ wsP)
{
    const int p = blockIdx.x;
    const int t = threadIdx.x;
    if (t < NNEG) {
        float s = 0.f, c = 0.f;
        for (int a = 0; a < 8; ++a) {
            const float* rec = recs + (size_t)(p * 8 + a) * REC;
            s += rec[t];
            c += rec[NNEG + t];
        }
        out[p * NNEG + t]          = s / (c + 1e-6f);
        out[OFF_FN + p * NNEG + t] = c;
    }
    if (t == 0) {
        float h = 0.f, ds = 0.f;
        for (int a = 0; a < 8; ++a) {
            const float* rec = recs + (size_t)(p * 8 + a) * REC;
            h  += rec[496];
            ds += rec[497];
        }
        out[OFF_HARD + p] = h * (1.0f / 256.0f);
        wsP[p] = ds;
    }
}

// ======================= launch =======================
extern "C" void kernel_launch(void* const* d_in, const int* in_sizes, int n_in,
                              void* d_out, int out_size, void* d_ws, size_t ws_size,
                              hipStream_t stream)
{
    const float* F     = (const float*)d_in[0];
    const int*   label = (const int*)d_in[1];
    float*       ws    = (float*)d_ws;
    float*       out   = (float*)d_out;
    float*       recs  = ws + R0;
    float*       wsP   = ws + P0;

    if (ws_size >= WS_NEED) {
        k_all <<<dim3(248),   dim3(1024), 0, stream>>>(F, label, recs);
        k_fin1<<<dim3(NPART), dim3(256),  0, stream>>>(recs, out, wsP);
        k_fin2<<<dim3(1),     dim3(64),   0, stream>>>(wsP, out);
    } else {
        fb_main<<<dim3(496),  dim3(256), 0, stream>>>(F, label, recs);
        fb_fin1<<<dim3(NPART), dim3(256), 0, stream>>>(recs, out, wsP);
        k_fin2<<<dim3(1),     dim3(64),  0, stream>>>(wsP, out);
    }
}